// Round 2
// baseline (94.295 us; speedup 1.0000x reference)
//
#include <hip/hip_runtime.h>
#include <math.h>

// GCDD fused: out = u + div( phi(G)*ux, phi(G)*uy ), 3x3 Sobel cross-correlations,
// zero padding at EVERY conv stage (intermediates forced to 0 outside the domain).
//
// Unified local coords: (r,c) with gy = ty0 + r - 4, gx = tx0 + c - 4.
//   su  valid rows [1,39) cols [0,40)   (u tile, halo 3 + 1 col pad for alignment)
//   sux/suy rows [2,38) cols [2,38)
//   sP/sQ   rows [3,37) cols [2,38)     (sP aliases su storage; residual u cached in regs)
//   out     rows [4,36) cols [4,36)
// Each thread owns one 4-wide x 1-tall micro-tile per stage (vectorized LDS access).

#define TILE 32
#define NT   384
#define LW   40

__global__ __launch_bounds__(NT) void gcdd_fused(
    const float* __restrict__ u, float* __restrict__ out, int H, int W)
{
    __shared__ float lds[4][LW * LW];
    float (*su)[LW]  = (float(*)[LW])lds[0];
    float (*sux)[LW] = (float(*)[LW])lds[1];
    float (*suy)[LW] = (float(*)[LW])lds[2];
    float (*sQ)[LW]  = (float(*)[LW])lds[3];
    float (*sP)[LW]  = su;  // alias: stage 3 overwrites u tile (residual cached in regs)

    const int tid = threadIdx.x;
    const int tx0 = blockIdx.x * TILE;
    const int ty0 = blockIdx.y * TILE;
    const long chan = blockIdx.z;
    const float* __restrict__ uc = u + chan * (long)H * W;
    float* __restrict__ oc = out + chan * (long)H * W;

    // ---- Stage 1: load u rows [1,39), cols [0,40) as float4 groups (38*10 = 380) ----
    const bool interior = (tx0 >= 4) && (tx0 + 36 <= W) && (ty0 >= 3) && (ty0 + 35 <= H);
    if (tid < 380) {
        const int r  = 1 + tid / 10;
        const int g  = tid % 10;
        const int gy = ty0 + r - 4;
        const int gxb = tx0 - 4 + g * 4;
        float4 v;
        if (interior) {
            v = *(const float4*)(uc + (long)gy * W + gxb);
        } else {
            float e[4];
            #pragma unroll
            for (int k = 0; k < 4; k++) {
                int gx = gxb + k;
                bool in = ((unsigned)gy < (unsigned)H) && ((unsigned)gx < (unsigned)W);
                e[k] = in ? uc[(long)gy * W + gx] : 0.f;
            }
            v = make_float4(e[0], e[1], e[2], e[3]);
        }
        *(float4*)&su[r][g * 4] = v;
    }
    __syncthreads();

    // ---- Stage 2: ux, uy on rows [2,38) x col-groups {2,6,...,34} (36*9 = 324 tiles) ----
    if (tid < 324) {
        const int r0 = 2 + tid / 9;
        const int c0 = 2 + 4 * (tid % 9);
        alignas(16) float a[3][8];
        #pragma unroll
        for (int j = 0; j < 3; j++) {
            *(float4*)&a[j][0] = *(const float4*)&su[r0 - 1 + j][c0 - 2];
            *(float4*)&a[j][4] = *(const float4*)&su[r0 - 1 + j][c0 + 2];
        }
        const int gy = ty0 + r0 - 4;
        const bool iny = (unsigned)gy < (unsigned)H;
        float vx[4], vy[4];
        #pragma unroll
        for (int dc = 0; dc < 4; dc++) {
            int gx = tx0 + c0 + dc - 4;
            bool in = iny && ((unsigned)gx < (unsigned)W);
            float A = a[0][dc + 1], B = a[0][dc + 2], C = a[0][dc + 3];
            float D = a[1][dc + 1],                  E = a[1][dc + 3];
            float F = a[2][dc + 1], G = a[2][dc + 2], Hv = a[2][dc + 3];
            float x = (C - A) + 2.f * (E - D) + (Hv - F);          // SOBEL_X
            float y = (F + 2.f * G + Hv) - (A + 2.f * B + C);      // SOBEL_Y
            vx[dc] = in ? x : 0.f;
            vy[dc] = in ? y : 0.f;
        }
        *(float2*)&sux[r0][c0]     = make_float2(vx[0], vx[1]);
        *(float2*)&sux[r0][c0 + 2] = make_float2(vx[2], vx[3]);
        *(float2*)&suy[r0][c0]     = make_float2(vy[0], vy[1]);
        *(float2*)&suy[r0][c0 + 2] = make_float2(vy[2], vy[3]);
    }
    // Residual u for stage 4, grabbed before sP overwrites su.
    float4 ures = make_float4(0.f, 0.f, 0.f, 0.f);
    if (tid < 256) {
        const int r4 = 4 + tid / 8;
        const int c4 = 4 + 4 * (tid % 8);
        ures = *(const float4*)&su[r4][c4];
    }
    __syncthreads();

    // ---- Stage 3: uxx,uxy,uyy -> G -> phi -> P,Q on rows [3,37) x cols {2,...,34} ----
    // (34*9 = 306 tiles; boundary cols 2 and 37 get halo-garbage values but are never read)
    if (tid < 306) {
        const int r0 = 3 + tid / 9;
        const int c0 = 2 + 4 * (tid % 9);
        alignas(16) float x[3][8], y[3][8];
        #pragma unroll
        for (int j = 0; j < 3; j++) {
            *(float4*)&x[j][0] = *(const float4*)&sux[r0 - 1 + j][c0 - 2];
            *(float4*)&x[j][4] = *(const float4*)&sux[r0 - 1 + j][c0 + 2];
            *(float4*)&y[j][0] = *(const float4*)&suy[r0 - 1 + j][c0 - 2];
            *(float4*)&y[j][4] = *(const float4*)&suy[r0 - 1 + j][c0 + 2];
        }
        const int gy = ty0 + r0 - 4;
        const bool iny = (unsigned)gy < (unsigned)H;
        float p[4], q[4];
        #pragma unroll
        for (int dc = 0; dc < 4; dc++) {
            int gx = tx0 + c0 + dc - 4;
            bool in = iny && ((unsigned)gx < (unsigned)W);
            float xm = x[1][dc + 2], ym = y[1][dc + 2];
            float uxx = (x[0][dc + 3] - x[0][dc + 1])
                + 2.f * (x[1][dc + 3] - x[1][dc + 1])
                +       (x[2][dc + 3] - x[2][dc + 1]);
            float uxy = (x[2][dc + 1] + 2.f * x[2][dc + 2] + x[2][dc + 3])
                      - (x[0][dc + 1] + 2.f * x[0][dc + 2] + x[0][dc + 3]);
            float uyy = (y[2][dc + 1] + 2.f * y[2][dc + 2] + y[2][dc + 3])
                      - (y[0][dc + 1] + 2.f * y[0][dc + 2] + y[0][dc + 3]);
            float den = 1.f + xm * xm + ym * ym;
            float d2 = den * den;
            float Gv = (uxx * uyy - uxy * uxy) * __builtin_amdgcn_rcpf(d2 + 1e-6f);
            float phi = __expf(-fabsf(Gv));
            p[dc] = in ? phi * xm : 0.f;
            q[dc] = in ? phi * ym : 0.f;
        }
        *(float2*)&sP[r0][c0]     = make_float2(p[0], p[1]);
        *(float2*)&sP[r0][c0 + 2] = make_float2(p[2], p[3]);
        *(float2*)&sQ[r0][c0]     = make_float2(q[0], q[1]);
        *(float2*)&sQ[r0][c0 + 2] = make_float2(q[2], q[3]);
    }
    __syncthreads();

    // ---- Stage 4: divergence + residual, rows [4,36) x col-groups {4,...,32} (256 tiles) ----
    if (tid < 256) {
        const int r0 = 4 + tid / 8;
        const int c0 = 4 + 4 * (tid % 8);
        alignas(16) float p[3][8], q[3][8];
        #pragma unroll
        for (int j = 0; j < 3; j++) {
            const int rr = r0 - 1 + j;
            *(float2*)&p[j][0] = *(const float2*)&sP[rr][c0 - 2];
            *(float2*)&p[j][2] = *(const float2*)&sP[rr][c0];
            *(float2*)&p[j][4] = *(const float2*)&sP[rr][c0 + 2];
            *(float2*)&p[j][6] = *(const float2*)&sP[rr][c0 + 4];
            *(float2*)&q[j][0] = *(const float2*)&sQ[rr][c0 - 2];
            *(float2*)&q[j][2] = *(const float2*)&sQ[rr][c0];
            *(float2*)&q[j][4] = *(const float2*)&sQ[rr][c0 + 2];
            *(float2*)&q[j][6] = *(const float2*)&sQ[rr][c0 + 4];
        }
        const float ur[4] = {ures.x, ures.y, ures.z, ures.w};
        float o[4];
        #pragma unroll
        for (int dc = 0; dc < 4; dc++) {
            float divx = (p[0][dc + 3] - p[0][dc + 1])
                 + 2.f * (p[1][dc + 3] - p[1][dc + 1])
                 +       (p[2][dc + 3] - p[2][dc + 1]);
            float divy = (q[2][dc + 1] + 2.f * q[2][dc + 2] + q[2][dc + 3])
                       - (q[0][dc + 1] + 2.f * q[0][dc + 2] + q[0][dc + 3]);
            o[dc] = ur[dc] + divx + divy;
        }
        const int gy = ty0 + r0 - 4;
        const int gx = tx0 + c0 - 4;
        *(float4*)(oc + (long)gy * W + gx) = make_float4(o[0], o[1], o[2], o[3]);
    }
}

extern "C" void kernel_launch(void* const* d_in, const int* in_sizes, int n_in,
                              void* d_out, int out_size, void* d_ws, size_t ws_size,
                              hipStream_t stream) {
    const float* u = (const float*)d_in[0];
    float* out = (float*)d_out;

    const int H = 512, W = 512;
    const int channels = in_sizes[0] / (H * W);  // B*C = 48

    dim3 grid(W / TILE, H / TILE, channels);
    dim3 block(NT);
    gcdd_fused<<<grid, block, 0, stream>>>(u, out, H, W);
}

// Round 3
// 63.321 us; speedup vs baseline: 1.4892x; 1.4892x over previous
//
#include <hip/hip_runtime.h>
#include <math.h>

// GCDD fused, LDS-minimal version.
// out = u + div( phi(G)*ux, phi(G)*uy ); 3x3 Sobel cross-correlations with zero
// padding at EVERY conv stage (intermediates forced to 0 outside the domain).
//
// Only u and P,Q live in LDS. ux,uy are recomputed in registers (rolling 3-row
// window) inside the phi stage — they cost ~6 VALU/point vs ~1 LDS b128 round
// trip each, and the LDS pipe (not VALU) was the measured bottleneck.
//
// Tile: 64 wide x 32 tall per block, 256 threads.
// Local coords: u   su[r][c]: gy=ty0+r-3 (r=0..37; rows 38,39 pad), gx=tx0+c-4
//               P,Q sP[r][c]: r=pr+1 (pr=-1..34), c=pc+2 (pc=-2..65)
//   stage-3 tasks: 17 col-groups x 9 row-quads = 153 threads, 4x4 P/Q each
//   stage-4 tasks: 16 col-groups x 8 row-quads = 128 threads, 4x4 out each
// Garbage containment: su pad rows 38,39 and sP/sQ rows 34,35 / col -2,65 are
// written-but-never-read; all *read* P/Q entries are exact.

#define TW 64
#define TH 32
#define NT 256

struct Smem {
    float su[40][72];
    float sP[36][68];
    float sQ[36][68];
};

template<bool EDGE>
__device__ __forceinline__ void stage3_compute(Smem* s, int tid, int tx0, int ty0,
                                               int H, int W) {
    if (tid >= 153) return;
    const int g   = tid % 17;
    const int rq  = tid / 17;
    const int srow = 4 * rq;            // su row of u row 0 of this task
    const int scol = 4 * g;             // su col of u col 0
    const int gyb = ty0 + 4 * rq - 3;   // gy of u row 0
    const int gxb = tx0 + 4 * g - 4;    // gx of u col 0

    float uw[3][8];            // rolling u rows
    float xw[3][6], yw[3][6];  // rolling ux,uy rows

    #pragma unroll
    for (int jr = 0; jr < 8; ++jr) {
        {
            float* w = uw[jr % 3];
            *(float4*)&w[0] = *(const float4*)&s->su[srow + jr][scol];
            *(float4*)&w[4] = *(const float4*)&s->su[srow + jr][scol + 4];
        }
        if (jr >= 2) {
            const int e = jr - 2;                 // ux/uy row idx (0..5), center u row jr-1
            const float* t = uw[(jr - 2) % 3];
            const float* m = uw[(jr - 1) % 3];
            const float* b = uw[jr % 3];
            float* xr = xw[e % 3];
            float* yr = yw[e % 3];
            #pragma unroll
            for (int c = 0; c < 6; ++c) {
                float A = t[c], B = t[c + 1], C = t[c + 2];
                float D = m[c],                E = m[c + 2];
                float F = b[c], Gg = b[c + 1], Hh = b[c + 2];
                float x = (C - A) + 2.f * (E - D) + (Hh - F);       // SOBEL_X
                float y = (F + 2.f * Gg + Hh) - (A + 2.f * B + C);  // SOBEL_Y
                if (EDGE) {
                    int gy = gyb + jr - 1;
                    int gx = gxb + c + 1;
                    bool in = ((unsigned)gy < (unsigned)H) & ((unsigned)gx < (unsigned)W);
                    x = in ? x : 0.f;
                    y = in ? y : 0.f;
                }
                xr[c] = x;
                yr[c] = y;
            }
            if (e >= 2) {
                const int mr = e - 2;             // P/Q row idx (0..3), pr = 4rq-1+mr
                const float* xt = xw[(e - 2) % 3];
                const float* xm = xw[(e - 1) % 3];
                const float* xb = xw[e % 3];
                const float* yt = yw[(e - 2) % 3];
                const float* ym = yw[(e - 1) % 3];
                const float* yb = yw[e % 3];
                float pv[4], qv[4];
                #pragma unroll
                for (int c = 0; c < 4; ++c) {
                    float xc = xm[c + 1], yc = ym[c + 1];
                    float uxx = (xt[c + 2] - xt[c]) + 2.f * (xm[c + 2] - xm[c])
                              + (xb[c + 2] - xb[c]);
                    float uxy = (xb[c] + 2.f * xb[c + 1] + xb[c + 2])
                              - (xt[c] + 2.f * xt[c + 1] + xt[c + 2]);
                    float uyy = (yb[c] + 2.f * yb[c + 1] + yb[c + 2])
                              - (yt[c] + 2.f * yt[c + 1] + yt[c + 2]);
                    float den = 1.f + xc * xc + yc * yc;
                    float Gq = (uxx * uyy - uxy * uxy)
                             * __builtin_amdgcn_rcpf(den * den + 1e-6f);
                    float phi = __expf(-fabsf(Gq));
                    float p = phi * xc, q = phi * yc;
                    if (EDGE) {
                        int gy = gyb + 2 + mr;   // = ty0 + pr
                        int gx = gxb + 2 + c;    // = tx0 + pc
                        bool in = ((unsigned)gy < (unsigned)H) & ((unsigned)gx < (unsigned)W);
                        p = in ? p : 0.f;
                        q = in ? q : 0.f;
                    }
                    pv[c] = p;
                    qv[c] = q;
                }
                *(float4*)&s->sP[srow + mr][scol] = make_float4(pv[0], pv[1], pv[2], pv[3]);
                *(float4*)&s->sQ[srow + mr][scol] = make_float4(qv[0], qv[1], qv[2], qv[3]);
            }
        }
    }
}

__global__ __launch_bounds__(NT) void gcdd_fused(
    const float* __restrict__ u, float* __restrict__ out, int H, int W)
{
    __shared__ Smem s;
    const int tid = threadIdx.x;
    const int tx0 = blockIdx.x * TW;
    const int ty0 = blockIdx.y * TH;
    const long chan = blockIdx.z;
    const float* __restrict__ uc = u + chan * (long)H * W;
    float* __restrict__ oc = out + chan * (long)H * W;

    const bool inr = (tx0 >= 4) && (tx0 + 68 <= W) && (ty0 >= 3) && (ty0 + 35 <= H);

    // ---- Stage 1: u tile -> LDS. 38 rows x 18 float4-groups (cols 0..71) ----
    for (int i = tid; i < 38 * 18; i += NT) {
        const int r = i / 18, g = i % 18;
        const int gy = ty0 + r - 3;
        const int gxb = tx0 + g * 4 - 4;
        float4 v;
        if (inr) {
            v = *(const float4*)(uc + (long)gy * W + gxb);
        } else {
            float e[4];
            #pragma unroll
            for (int k = 0; k < 4; ++k) {
                const int gx = gxb + k;
                const bool in = ((unsigned)gy < (unsigned)H) & ((unsigned)gx < (unsigned)W);
                e[k] = in ? uc[(long)gy * W + gx] : 0.f;
            }
            v = make_float4(e[0], e[1], e[2], e[3]);
        }
        *(float4*)&s.su[r][g * 4] = v;
    }
    __syncthreads();

    // ---- Stage 3 (fused ux/uy recompute + curvature + phi): P,Q -> LDS ----
    if (inr) stage3_compute<false>(&s, tid, tx0, ty0, H, W);
    else     stage3_compute<true >(&s, tid, tx0, ty0, H, W);
    __syncthreads();

    // ---- Stage 4: divergence + residual. 128 tasks of 4x4 outputs ----
    if (tid < 128) {
        const int g  = tid % 16;
        const int rq = tid / 16;
        const int prow = 4 * rq;   // sP rows prow..prow+5
        const int pcol = 4 * g;    // sP cols pcol..pcol+7
        const long obase = (long)(ty0 + 4 * rq) * W + (tx0 + 4 * g);

        float pw[3][8], qw[3][8];
        #pragma unroll
        for (int j = 0; j < 6; ++j) {
            {
                float* pr_ = pw[j % 3];
                float* qr_ = qw[j % 3];
                *(float4*)&pr_[0] = *(const float4*)&s.sP[prow + j][pcol];
                *(float4*)&pr_[4] = *(const float4*)&s.sP[prow + j][pcol + 4];
                *(float4*)&qr_[0] = *(const float4*)&s.sQ[prow + j][pcol];
                *(float4*)&qr_[4] = *(const float4*)&s.sQ[prow + j][pcol + 4];
            }
            if (j >= 2) {
                const int m = j - 2;                 // output row m (0..3)
                const float* pt = pw[(j - 2) % 3];
                const float* pm = pw[(j - 1) % 3];
                const float* pb = pw[j % 3];
                const float* qt = qw[(j - 2) % 3];
                const float* qb = qw[j % 3];
                const float4 ur = *(const float4*)&s.su[prow + 3 + m][pcol + 4];
                const float urv[4] = {ur.x, ur.y, ur.z, ur.w};
                float o[4];
                #pragma unroll
                for (int c = 0; c < 4; ++c) {
                    float divx = (pt[c + 3] - pt[c + 1])
                         + 2.f * (pm[c + 3] - pm[c + 1])
                         +       (pb[c + 3] - pb[c + 1]);
                    float divy = (qb[c + 1] + 2.f * qb[c + 2] + qb[c + 3])
                               - (qt[c + 1] + 2.f * qt[c + 2] + qt[c + 3]);
                    o[c] = urv[c] + divx + divy;
                }
                *(float4*)(oc + obase + (long)m * W) = make_float4(o[0], o[1], o[2], o[3]);
            }
        }
    }
}

extern "C" void kernel_launch(void* const* d_in, const int* in_sizes, int n_in,
                              void* d_out, int out_size, void* d_ws, size_t ws_size,
                              hipStream_t stream) {
    const float* u = (const float*)d_in[0];
    float* out = (float*)d_out;

    const int H = 512, W = 512;
    const int channels = in_sizes[0] / (H * W);  // B*C = 48

    dim3 grid(W / TW, H / TH, channels);
    dim3 block(NT);
    gcdd_fused<<<grid, block, 0, stream>>>(u, out, H, W);
}